// Round 6
// baseline (132.176 us; speedup 1.0000x reference)
//
#include <hip/hip_runtime.h>

// LSTM: B=16384, T=1024, I=1, H=2, C=4.
// 2 lanes per batch element: lane (2e+j) owns hidden unit j of element e.
// All gate math for unit j is lane-local (4 exp2 + 2 rcp per step/lane);
// the recurrent cross-unit h is exchanged with one __shfl_xor (quad_perm DPP).
//
// R6 change vs R5: the float4 x-load is explicitly double-buffered
// (prefetch next group at top of body, consume previous group), so the
// ~500-900 cyc streaming-load latency hides under the ~1200 cyc of serial
// recurrence compute per 4-step group instead of stalling the chain every
// iteration. Plus a minor chain trim: tanh argument computed as
// (TANH_SCALE*num)*rcp(den), with the scale-mul issued during the rcp.
//
// Gate rows (PyTorch order): i: 0,1  f: 2,3  g: 4,5  o: 6,7
// Merged-reciprocal activations (exp2-scale folded into weights):
//   E_k = exp2(s_k*pre_k), s_k = -log2(e) for i,f,o ; +2*log2(e) for g
//   c' = [c*(1+Ei)(1+Eg) + (Eg-1)(1+Ef)] / [(1+Ef)(1+Ei)(1+Eg)]   (1 rcp)
//   h' = (Ec-1)/[(1+Eo)(Ec+1)], Ec = exp2(med3(2log2e*c', -30, 30)) (1 rcp)

typedef float f32x2 __attribute__((ext_vector_type(2)));

static __device__ __forceinline__ float fast_exp2(float x) { return __builtin_amdgcn_exp2f(x); }
static __device__ __forceinline__ float fast_rcp(float x)  { return __builtin_amdgcn_rcpf(x); }

#define SIG_SCALE  (-1.4426950408889634f)  // -log2(e)
#define TANH_SCALE ( 2.8853900817779268f)  // 2*log2(e)

__global__ __launch_bounds__(64, 1) void lstm_fused2(
    const float* __restrict__ x,      // [B, T, 1]
    const float* __restrict__ W_ih,   // [8, 1]
    const float* __restrict__ W_hh,   // [8, 2]
    const float* __restrict__ b_ih,   // [8]
    const float* __restrict__ b_hh,   // [8]
    const float* __restrict__ W_fc,   // [4, 2]
    const float* __restrict__ b_fc,   // [4]
    float* __restrict__ out,          // [B, 4]
    int T)
{
    const int tid = blockIdx.x * 64 + threadIdx.x;
    const int e   = tid >> 1;          // batch element
    const int j   = tid & 1;           // hidden unit owned by this lane

    // Per-lane scaled weights for my unit's 4 gates (k: 0=i,1=f,2=g,3=o).
    // whm multiplies MY h, whp multiplies my PARTNER's h.
    float wihs[4], whm[4], whp[4], bbs[4];
#pragma unroll
    for (int k = 0; k < 4; ++k) {
        const int g = 2 * k + j;                         // gate row
        const float s = (k == 2) ? TANH_SCALE : SIG_SCALE;
        wihs[k] = s * W_ih[g];
        whm[k]  = s * W_hh[2 * g + j];
        whp[k]  = s * W_hh[2 * g + (j ^ 1)];
        bbs[k]  = s * (b_ih[g] + b_hh[g]);
    }

    // Packed views for v_pk_fma_f32 on the pre-activation math.
    f32x2 wihs2[2], whm2[2], whp2[2], bbs2[2];
#pragma unroll
    for (int q = 0; q < 2; ++q) {
        wihs2[q] = f32x2{wihs[2*q], wihs[2*q+1]};
        whm2[q]  = f32x2{whm[2*q],  whm[2*q+1]};
        whp2[q]  = f32x2{whp[2*q],  whp[2*q+1]};
        bbs2[q]  = f32x2{bbs[2*q],  bbs[2*q+1]};
    }

    float hm = 0.f;   // my unit's h
    float hp = 0.f;   // partner unit's h
    float c  = 0.f;   // my unit's c

    const float4* xv = reinterpret_cast<const float4*>(x + (size_t)e * (size_t)T);
    const int nt4 = T >> 2;

    // Software pipeline: cur holds the group being consumed; nxt is in
    // flight while the 4 recurrence steps (~1200 cyc serial chain) run.
    float4 cur = xv[0];

    for (int t4 = 0; t4 < nt4; ++t4) {
        const int nidx = (t4 + 1 < nt4) ? (t4 + 1) : t4;   // clamp: no OOB
        const float4 nxt = xv[nidx];

        const float xs[4] = {cur.x, cur.y, cur.z, cur.w};

        // h-independent x-terms for 4 timesteps (packed fma).
        f32x2 xterm[4][2];
#pragma unroll
        for (int u = 0; u < 4; ++u) {
            const f32x2 xu = f32x2{xs[u], xs[u]};
#pragma unroll
            for (int q = 0; q < 2; ++q)
                xterm[u][q] = __builtin_elementwise_fma(xu, wihs2[q], bbs2[q]);
        }

#pragma unroll
        for (int u = 0; u < 4; ++u) {
            const f32x2 hmv = f32x2{hm, hm};
            const f32x2 hpv = f32x2{hp, hp};
            const f32x2 pre01 = __builtin_elementwise_fma(
                whm2[0], hmv, __builtin_elementwise_fma(whp2[0], hpv, xterm[u][0]));
            const f32x2 pre23 = __builtin_elementwise_fma(
                whm2[1], hmv, __builtin_elementwise_fma(whp2[1], hpv, xterm[u][1]));

            const float Ei = fast_exp2(pre01.x);
            const float Ef = fast_exp2(pre01.y);
            const float Eg = fast_exp2(pre23.x);
            const float Eo = fast_exp2(pre23.y);

            const float F    = 1.f + Ef;
            const float Gp   = 1.f + Eg;
            const float P    = fmaf(Ei, Gp, Gp);           // (1+Ei)(1+Eg)
            const float GmF  = fmaf(Eg, F, -F);            // (Eg-1)(1+Ef)
            const float num  = fmaf(c, P, GmF);
            const float den  = F * P;
            const float r    = fast_rcp(den);
            const float Tnum = TANH_SCALE * num;           // issues during rcp
            c = num * r;                                   // off the h-chain

            const float a  = __builtin_amdgcn_fmed3f(Tnum * r, -30.f, 30.f);
            const float Ec = fast_exp2(a);
            const float dh = (1.f + Eo) * (Ec + 1.f);
            const float r2 = fast_rcp(dh);
            hm = fmaf(Ec, r2, -r2);                        // tanh(c)*sigmoid(o)

            hp = __shfl_xor(hm, 1, 64);                    // quad_perm DPP swap
        }

        cur = nxt;   // consume the prefetched group next iteration
    }

    // Final FC: out[e,:] = h @ W_fc^T + b_fc.  Even lane -> classes 0,1;
    // odd lane -> classes 2,3. Lane pair writes one contiguous 16B row.
    const float h0 = j ? hp : hm;
    const float h1 = j ? hm : hp;
    const int   c0 = 2 * j;
    const float o0 = fmaf(W_fc[2*c0+0], h0, fmaf(W_fc[2*c0+1], h1, b_fc[c0]));
    const float o1 = fmaf(W_fc[2*c0+2], h0, fmaf(W_fc[2*c0+3], h1, b_fc[c0+1]));
    float2 r2; r2.x = o0; r2.y = o1;
    reinterpret_cast<float2*>(out)[e * 2 + j] = r2;
}

extern "C" void kernel_launch(void* const* d_in, const int* in_sizes, int n_in,
                              void* d_out, int out_size, void* d_ws, size_t ws_size,
                              hipStream_t stream) {
    const float* x    = (const float*)d_in[0];
    const float* W_ih = (const float*)d_in[1];
    const float* W_hh = (const float*)d_in[2];
    const float* b_ih = (const float*)d_in[3];
    const float* b_hh = (const float*)d_in[4];
    const float* W_fc = (const float*)d_in[5];
    const float* b_fc = (const float*)d_in[6];
    float* out = (float*)d_out;

    const int T = 1024;
    const int B = in_sizes[0] / T;   // I == 1

    dim3 block(64);
    dim3 grid((B * 2) / 64);         // 2 lanes/element -> 512 waves, 2 waves/CU
    lstm_fused2<<<grid, block, 0, stream>>>(x, W_ih, W_hh, b_ih, b_hh, W_fc, b_fc, out, T);
}

// Round 7
// 105.882 us; speedup vs baseline: 1.2483x; 1.2483x over previous
//
#include <hip/hip_runtime.h>

// LSTM: B=16384, T=1024, I=1, H=2, C=4.
// 2 lanes per batch element: lane (2e+j) owns hidden unit j of element e.
//
// R7 changes vs R5/R6 (chain surgery — we are latency-bound on the serial
// per-step dependency chain, 304 cy/step measured):
//  1. Cross-lane h exchange: __shfl_xor (ds_bpermute, LDS-path latency on
//     the chain) -> v_mov_b32 DPP quad_perm:[1,0,3,2] (~4 cy VALU).
//  2. h-path tanh: exp2+rcp stage pair -> Pade[7/6] rational of tanh with
//     a med3 clamp at |z|<=5, sigma(o) folded into the same denominator.
//     Chain goes 4 serial trans stages -> 3. c-path math is unchanged
//     (identical A/B merged form, c' = A*rcp(B)).
//
// Gate rows (PyTorch order): i: 0,1  f: 2,3  g: 4,5  o: 6,7
//   Ei=e^-i, Ef=e^-f (SIG_SCALE folded), Eg=e^{2g} (TANH_SCALE folded),
//   Eo=e^-o.  c' = A/B, A = (c*(1+Ei))*(1+Eg) + (Eg-1)(1+Ef),
//   B = (1+Ef)(1+Ei)(1+Eg).
//   h' = tanh(c')*sigma(o) = zc*P(zc^2) * rcp(Q(zc^2)*(1+Eo)),
//   zc = med3(c',-5,5), P/Q = Pade[7/6] tanh coefficients.

typedef float f32x2 __attribute__((ext_vector_type(2)));

static __device__ __forceinline__ float fast_exp2(float x) { return __builtin_amdgcn_exp2f(x); }
static __device__ __forceinline__ float fast_rcp(float x)  { return __builtin_amdgcn_rcpf(x); }

// Swap values between lane pairs (0<->1, 2<->3, ...) via DPP quad_perm.
// dpp_ctrl 0xB1 = quad_perm:[1,0,3,2]; row_mask=0xF, bank_mask=0xF.
static __device__ __forceinline__ float dpp_swap1(float v) {
    int i = __builtin_bit_cast(int, v);
    i = __builtin_amdgcn_mov_dpp(i, 0xB1, 0xF, 0xF, false);
    return __builtin_bit_cast(float, i);
}

#define SIG_SCALE  (-1.4426950408889634f)  // -log2(e)
#define TANH_SCALE ( 2.8853900817779268f)  // 2*log2(e)

__global__ __launch_bounds__(64, 1) void lstm_fused3(
    const float* __restrict__ x,      // [B, T, 1]
    const float* __restrict__ W_ih,   // [8, 1]
    const float* __restrict__ W_hh,   // [8, 2]
    const float* __restrict__ b_ih,   // [8]
    const float* __restrict__ b_hh,   // [8]
    const float* __restrict__ W_fc,   // [4, 2]
    const float* __restrict__ b_fc,   // [4]
    float* __restrict__ out,          // [B, 4]
    int T)
{
    const int tid = blockIdx.x * 64 + threadIdx.x;
    const int e   = tid >> 1;          // batch element
    const int j   = tid & 1;           // hidden unit owned by this lane

    // Per-lane scaled weights for my unit's 4 gates (k: 0=i,1=f,2=g,3=o).
    // whm multiplies MY h, whp multiplies my PARTNER's h.
    float wihs[4], whm[4], whp[4], bbs[4];
#pragma unroll
    for (int k = 0; k < 4; ++k) {
        const int g = 2 * k + j;                         // gate row
        const float s = (k == 2) ? TANH_SCALE : SIG_SCALE;
        wihs[k] = s * W_ih[g];
        whm[k]  = s * W_hh[2 * g + j];
        whp[k]  = s * W_hh[2 * g + (j ^ 1)];
        bbs[k]  = s * (b_ih[g] + b_hh[g]);
    }

    // Packed views for v_pk_fma_f32 on the pre-activation math.
    f32x2 wihs2[2], whm2[2], whp2[2], bbs2[2];
#pragma unroll
    for (int q = 0; q < 2; ++q) {
        wihs2[q] = f32x2{wihs[2*q], wihs[2*q+1]};
        whm2[q]  = f32x2{whm[2*q],  whm[2*q+1]};
        whp2[q]  = f32x2{whp[2*q],  whp[2*q+1]};
        bbs2[q]  = f32x2{bbs[2*q],  bbs[2*q+1]};
    }

    float hm = 0.f;   // my unit's h
    float hp = 0.f;   // partner unit's h
    float c  = 0.f;   // my unit's c

    const float4* xv = reinterpret_cast<const float4*>(x + (size_t)e * (size_t)T);
    const int nt4 = T >> 2;

    for (int t4 = 0; t4 < nt4; ++t4) {
        const float4 xq = xv[t4];
        const float xs[4] = {xq.x, xq.y, xq.z, xq.w};

        // h-independent x-terms for 4 timesteps (packed fma).
        f32x2 xterm[4][2];
#pragma unroll
        for (int u = 0; u < 4; ++u) {
            const f32x2 xu = f32x2{xs[u], xs[u]};
#pragma unroll
            for (int q = 0; q < 2; ++q)
                xterm[u][q] = __builtin_elementwise_fma(xu, wihs2[q], bbs2[q]);
        }

#pragma unroll
        for (int u = 0; u < 4; ++u) {
            const f32x2 hmv = f32x2{hm, hm};
            const f32x2 hpv = f32x2{hp, hp};
            const f32x2 pre01 = __builtin_elementwise_fma(
                whm2[0], hmv, __builtin_elementwise_fma(whp2[0], hpv, xterm[u][0]));
            const f32x2 pre23 = __builtin_elementwise_fma(
                whm2[1], hmv, __builtin_elementwise_fma(whp2[1], hpv, xterm[u][1]));

            // Gate exps: g,f,i needed first (feed A,B); o only needed late.
            const float Eg = fast_exp2(pre23.x);
            const float Ef = fast_exp2(pre01.y);
            const float Ei = fast_exp2(pre01.x);
            const float Eo = fast_exp2(pre23.y);

            const float F   = 1.f + Ef;
            const float Gp  = 1.f + Eg;
            const float Ip  = 1.f + Ei;
            const float Oo  = 1.f + Eo;

            const float GmF = fmaf(Eg, F, -F);             // (Eg-1)(1+Ef)
            const float cp  = c * Ip;
            const float B   = (F * Ip) * Gp;
            const float A   = fmaf(cp, Gp, GmF);

            const float rB  = fast_rcp(B);
            c = A * rB;                                    // new cell state

            // h' = tanh(zc)*sigma(o), Pade[7/6], zc = clamp(c, +-5)
            const float zc = __builtin_amdgcn_fmed3f(c, -5.f, 5.f);
            const float uu = zc * zc;
            const float p3 = fmaf(fmaf(uu + 378.f, uu, 17325.f), uu, 135135.f);
            const float q3 = fmaf(fmaf(fmaf(28.f, uu, 3150.f), uu, 62370.f), uu, 135135.f);
            const float numer = zc * p3;
            const float D     = q3 * Oo;
            const float rD    = fast_rcp(D);
            hm = numer * rD;

            hp = dpp_swap1(hm);                            // lane-pair swap
        }
    }

    // Final FC: out[e,:] = h @ W_fc^T + b_fc.  Even lane -> classes 0,1;
    // odd lane -> classes 2,3. Lane pair writes one contiguous 16B row.
    const float h0 = j ? hp : hm;
    const float h1 = j ? hm : hp;
    const int   c0 = 2 * j;
    const float o0 = fmaf(W_fc[2*c0+0], h0, fmaf(W_fc[2*c0+1], h1, b_fc[c0]));
    const float o1 = fmaf(W_fc[2*c0+2], h0, fmaf(W_fc[2*c0+3], h1, b_fc[c0+1]));
    float2 r2; r2.x = o0; r2.y = o1;
    reinterpret_cast<float2*>(out)[e * 2 + j] = r2;
}

extern "C" void kernel_launch(void* const* d_in, const int* in_sizes, int n_in,
                              void* d_out, int out_size, void* d_ws, size_t ws_size,
                              hipStream_t stream) {
    const float* x    = (const float*)d_in[0];
    const float* W_ih = (const float*)d_in[1];
    const float* W_hh = (const float*)d_in[2];
    const float* b_ih = (const float*)d_in[3];
    const float* b_hh = (const float*)d_in[4];
    const float* W_fc = (const float*)d_in[5];
    const float* b_fc = (const float*)d_in[6];
    float* out = (float*)d_out;

    const int T = 1024;
    const int B = in_sizes[0] / T;   // I == 1

    dim3 block(64);
    dim3 grid((B * 2) / 64);         // 2 lanes/element -> 512 waves, 2 waves/CU
    lstm_fused3<<<grid, block, 0, stream>>>(x, W_ih, W_hh, b_ih, b_hh, W_fc, b_fc, out, T);
}